// Round 3
// baseline (9705.891 us; speedup 1.0000x reference)
//
#include <hip/hip_runtime.h>

#define D_  1280
#define T_  2048
#define B_  16
#define NW  40     // scan workgroups
#define RPW 32     // W_h rows per scan workgroup
#define KS  320    // K-slice per wave in scan
#define FSTR 272   // flag replica stride in u32 (1088 B, odd # of 64B lines)

typedef unsigned short u16;
typedef unsigned int   u32;
typedef unsigned long long u64;
typedef __attribute__((ext_vector_type(8))) short bf16x8;   // 8 bf16 = 4 VGPRs
typedef __attribute__((ext_vector_type(4))) float f32x4;
typedef __attribute__((ext_vector_type(4))) int   i32x4;

__device__ __forceinline__ float bf2f(u16 u) {
  union { u32 i; float f; } v; v.i = ((u32)u) << 16; return v.f;
}
__device__ __forceinline__ u16 f2bf(float f) {
  union { float f; u32 i; } v; v.f = f;
  u32 r = v.i + 0x7fffu + ((v.i >> 16) & 1u);   // RNE
  return (u16)(r >> 16);
}
__device__ __forceinline__ float sigm(float x) { return 1.f / (1.f + __expf(-x)); }
__device__ __forceinline__ float tanh_(float x) { return 1.f - 2.f / (__expf(2.f * x) + 1.f); }

// ---------------------------------------------------------------------------
// dtype detection: bf16 halfwords of N(0,1)-scale data have exponent field in
// ~[100,140] nearly always; fp32 low-halfwords are ~random -> count separates.
// ---------------------------------------------------------------------------
__global__ void detect_k(const u16* __restrict__ x, int* __restrict__ dflag) {
  __shared__ int cnt;
  if (threadIdx.x == 0) cnt = 0;
  __syncthreads();
  u16 u = x[threadIdx.x];
  int e = (u >> 7) & 0xFF;
  if (e >= 100 && e <= 140) atomicAdd(&cnt, 1);
  __syncthreads();
  if (threadIdx.x == 0) *dflag = (cnt < 192) ? 1 : 0;   // 1 = fp32 inputs
}

// convert (or copy) n elements to bf16; n arbitrary, 8 elems/thread
__global__ void cvt_k(const void* __restrict__ src, u16* __restrict__ dst,
                      long n, const int* __restrict__ dflag) {
  const int fp32 = *dflag;
  long base = ((long)blockIdx.x * 256 + threadIdx.x) * 8;
  if (base + 8 <= n) {
    if (fp32) {
      const float* s = (const float*)src;
      f32x4 f0 = *(const f32x4*)(s + base);
      f32x4 f1 = *(const f32x4*)(s + base + 4);
      u32 w0 = (u32)f2bf(f0[0]) | ((u32)f2bf(f0[1]) << 16);
      u32 w1 = (u32)f2bf(f0[2]) | ((u32)f2bf(f0[3]) << 16);
      u32 w2 = (u32)f2bf(f1[0]) | ((u32)f2bf(f1[1]) << 16);
      u32 w3 = (u32)f2bf(f1[2]) | ((u32)f2bf(f1[3]) << 16);
      i32x4 o = { (int)w0, (int)w1, (int)w2, (int)w3 };
      *(i32x4*)(dst + base) = o;
    } else {
      *(i32x4*)(dst + base) = *(const i32x4*)((const u16*)src + base);
    }
  } else {
    for (long i = base; i < n; ++i)
      dst[i] = fp32 ? f2bf(((const float*)src)[i]) : ((const u16*)src)[i];
  }
}

// ---------------------------------------------------------------------------
// GEMM: C(M x N) = A(M x K=1280) * B^T, B given as (N x K) row-major bf16.
// 128x128 tile, BK=32, 256 threads = 4 waves in 2x2 grid, 64x64 per wave.
// ---------------------------------------------------------------------------
template<int EPI>
__global__ __launch_bounds__(256, 2) void gemm_bt(
    const u16* __restrict__ A, const u16* __restrict__ B,
    u16* __restrict__ C0, u16* __restrict__ C1,
    const u16* __restrict__ bias,
    void* __restrict__ Cout, const int* __restrict__ dflag)
{
  __shared__ __align__(16) u16 As[128 * 40];
  __shared__ __align__(16) u16 Bs[128 * 40];

  const int fp32o = (EPI == 2) ? *dflag : 0;
  const int tid  = threadIdx.x;
  const int lane = tid & 63;
  const int qq   = lane >> 4, ln = lane & 15;
  const int wave = tid >> 6;
  const int wm   = (wave >> 1) * 64, wn = (wave & 1) * 64;
  const long m0  = (long)blockIdx.y * 128;
  const long n0  = (long)blockIdx.x * 128;

  const int r0 = tid >> 2, c0 = (tid & 3) * 8;
  const int r1 = r0 + 64;

  f32x4 acc[4][4];
  #pragma unroll
  for (int i = 0; i < 4; ++i)
    #pragma unroll
    for (int j = 0; j < 4; ++j) acc[i][j] = (f32x4){0.f, 0.f, 0.f, 0.f};

  for (int kt = 0; kt < D_; kt += 32) {
    i32x4 av0 = *(const i32x4*)(A + (m0 + r0) * D_ + kt + c0);
    i32x4 av1 = *(const i32x4*)(A + (m0 + r1) * D_ + kt + c0);
    i32x4 bv0 = *(const i32x4*)(B + (n0 + r0) * D_ + kt + c0);
    i32x4 bv1 = *(const i32x4*)(B + (n0 + r1) * D_ + kt + c0);
    __syncthreads();                       // previous iter's ds_reads done
    *(i32x4*)(As + r0 * 40 + c0) = av0;
    *(i32x4*)(As + r1 * 40 + c0) = av1;
    *(i32x4*)(Bs + r0 * 40 + c0) = bv0;
    *(i32x4*)(Bs + r1 * 40 + c0) = bv1;
    __syncthreads();

    bf16x8 af[4], bfr[4];
    #pragma unroll
    for (int i = 0; i < 4; ++i)
      af[i] = *(const bf16x8*)(As + (wm + i * 16 + ln) * 40 + qq * 8);
    #pragma unroll
    for (int j = 0; j < 4; ++j)
      bfr[j] = *(const bf16x8*)(Bs + (wn + j * 16 + ln) * 40 + qq * 8);
    #pragma unroll
    for (int i = 0; i < 4; ++i)
      #pragma unroll
      for (int j = 0; j < 4; ++j)
        acc[i][j] = __builtin_amdgcn_mfma_f32_16x16x32_bf16(af[i], bfr[j], acc[i][j], 0, 0, 0);
  }

  #pragma unroll
  for (int i = 0; i < 4; ++i)
    #pragma unroll
    for (int j = 0; j < 4; ++j)
      #pragma unroll
      for (int r = 0; r < 4; ++r) {
        long m = m0 + wm + i * 16 + qq * 4 + r;       // C/D: row = quad*4+reg
        long n = n0 + wn + j * 16 + ln;               //      col = lane&15
        float v = acc[i][j][r];
        if (EPI == 0) {
          float s = v * sigm(v);                      // silu
          long t = m & 2047, bb = m >> 11;
          if (n < D_) C0[m * D_ + n] = f2bf(s);                       // x_proj (b,t,d)
          else        C1[(t * 16 + bb) * D_ + (n - D_)] = f2bf(s);    // silu(z) (t,b,d)
        } else if (EPI == 1) {
          long t = m & 2047, bb = m >> 11;
          C0[(t * 16 + bb) * D_ + n] = f2bf(v + bf2f(bias[n]));       // x_pre (t,b,d)
        } else {
          long bb = m & 15, t = m >> 4;
          long idx = (bb * 2048 + t) * D_ + n;                        // out (b,t,d)
          if (fp32o) ((float*)Cout)[idx] = v;
          else       ((u16*)Cout)[idx]   = f2bf(v);
        }
      }
}

// ---------------------------------------------------------------------------
// Sequential scan. Cross-WG h moves via relaxed agent-scope atomics meeting at
// the LIC. Publication is PER-WAVE: each wave stores its h slice, drains its
// own vmcnt (store acks = data at coherence point), then bumps its monotone
// flag in ALL 40 per-consumer-WG REPLICAS with a single per-lane store
// (lanes 0..39 -> 40 distinct lines, fire-and-forget). Consumer WG g polls
// ONLY replica g: per-region load pressure drops 160 waves -> 4, so producer
// flag stores no longer queue behind a 160-wave poll flood on 3 shared lines
// (r2's residual bottleneck theory). Flags are monotone (>= compare, no ABA,
// no re-zeroing) and permanently LIC-hot.
// Ring safety (2-deep, no global barrier): h^(t+1) stores happen after the
// WG's LDS-reduce barrier, which all 4 sibling waves reach only after their
// polls for step t; the union of sibling poll-sets is ALL 160 wave-flags, so
// any h^(t+1) store implies every wave everywhere finished reading h^(t-1).
// sout aliases xpre (read-before-write at same address by same thread).
// ---------------------------------------------------------------------------
__global__ __launch_bounds__(256, 1) void scan_rnn(
    const u16* __restrict__ Wh, const u16* __restrict__ xpre,
    const u16* __restrict__ zs, u16* __restrict__ sout,
    u16* __restrict__ hbuf, u32* __restrict__ flags,
    void* __restrict__ dout, const int* __restrict__ dflag)
{
  const int fp32o = *dflag;
  const int wg   = blockIdx.x;
  const int tid  = threadIdx.x;
  const int lane = tid & 63;
  const int wave = tid >> 6;
  const int qq   = lane >> 4, ln = lane & 15;

  // persistent W_h fragments: A[m=lane&15][k=quad*8+j], rows wg*32 + i*16 + ln
  bf16x8 wfrag[2][10];
  #pragma unroll
  for (int i = 0; i < 2; ++i) {
    const u16* wrow = Wh + (long)(wg * RPW + i * 16 + ln) * D_ + wave * KS;
    #pragma unroll
    for (int c = 0; c < 10; ++c)
      wfrag[i][c] = *(const bf16x8*)(wrow + c * 32 + qq * 8);
  }

  // double-buffered cross-wave reduce: one __syncthreads per step
  __shared__ float red[2][2176];   // [wave*2+tile]*272 + row*17 + batch (17-pad)

  const int batch = tid >> 4;
  const int dl0   = (tid & 15) * 2;
  const int d0    = wg * RPW + dl0;
  const int tile  = dl0 >> 4;
  const int row0  = dl0 & 15;

  // poll address: my WG's replica, one hot dword per lane (lanes 0..39)
  const u32* fl = flags + (long)wg * FSTR + 40 * wave + ((lane < 40) ? lane : 0);
  // publish address: replica = my lane, slot = my producer-wave id
  u32* fs = flags + (long)lane * FSTR + (wg * 4 + wave);

  // per-lane h-load base (u64 units): row ln, k-slice wave*KS, sub qq*8 bf16
  const long hload = (long)ln * 320 + wave * 80 + qq * 2;

  // preload step-0 inputs (h-independent)
  long pidx = (long)(0 * B_ + batch) * D_ + d0;
  u32 xp2 = *(const u32*)(xpre + pidx);
  u32 zs2 = *(const u32*)(zs + pidx);

  for (int t = 0; t < T_; ++t) {
    const u64* hc = (const u64*)(hbuf + (t & 1) * (B_ * D_));
    u16*       hn = hbuf + ((t + 1) & 1) * (B_ * D_);

    // --- poll my replica's 40 producer-wave flags (4 waves/region only) ---
    {
      const u32 tgt = (u32)t;
      for (;;) {
        u32 v = __hip_atomic_load(fl, __ATOMIC_RELAXED, __HIP_MEMORY_SCOPE_AGENT);
        if (__all(v >= tgt)) break;
      }
    }

    // --- bulk-load my h^t slice: 20 x 8B bypass loads, one latency ---
    const u64* hr = hc + hload;
    u64 hq[20];
    #pragma unroll
    for (int c = 0; c < 10; ++c) {
      hq[c * 2 + 0] = __hip_atomic_load(hr + c * 8 + 0,
                          __ATOMIC_RELAXED, __HIP_MEMORY_SCOPE_AGENT);
      hq[c * 2 + 1] = __hip_atomic_load(hr + c * 8 + 1,
                          __ATOMIC_RELAXED, __HIP_MEMORY_SCOPE_AGENT);
    }

    // --- MFMA accumulate: 4 independent 5-deep chains (halved dep latency) ---
    f32x4 a0 = (f32x4){0.f,0.f,0.f,0.f}, a1 = (f32x4){0.f,0.f,0.f,0.f};
    f32x4 b0 = (f32x4){0.f,0.f,0.f,0.f}, b1 = (f32x4){0.f,0.f,0.f,0.f};
    #pragma unroll
    for (int c = 0; c < 10; c += 2) {
      union { u64 q[2]; bf16x8 v; } hu0, hu1;
      hu0.q[0] = hq[c * 2 + 0];
      hu0.q[1] = hq[c * 2 + 1];
      hu1.q[0] = hq[c * 2 + 2];
      hu1.q[1] = hq[c * 2 + 3];
      a0 = __builtin_amdgcn_mfma_f32_16x16x32_bf16(wfrag[0][c],     hu0.v, a0, 0, 0, 0);
      a1 = __builtin_amdgcn_mfma_f32_16x16x32_bf16(wfrag[1][c],     hu0.v, a1, 0, 0, 0);
      b0 = __builtin_amdgcn_mfma_f32_16x16x32_bf16(wfrag[0][c + 1], hu1.v, b0, 0, 0, 0);
      b1 = __builtin_amdgcn_mfma_f32_16x16x32_bf16(wfrag[1][c + 1], hu1.v, b1, 0, 0, 0);
    }
    a0 += b0;
    a1 += b1;

    float* rw = red[t & 1];
    #pragma unroll
    for (int r = 0; r < 4; ++r) {
      rw[(wave * 2 + 0) * 272 + (qq * 4 + r) * 17 + ln] = a0[r];
      rw[(wave * 2 + 1) * 272 + (qq * 4 + r) * 17 + ln] = a1[r];
    }
    __syncthreads();

    float s0 = rw[(0 + tile) * 272 + row0 * 17 + batch]
             + rw[(2 + tile) * 272 + row0 * 17 + batch]
             + rw[(4 + tile) * 272 + row0 * 17 + batch]
             + rw[(6 + tile) * 272 + row0 * 17 + batch];
    float s1 = rw[(0 + tile) * 272 + (row0 + 1) * 17 + batch]
             + rw[(2 + tile) * 272 + (row0 + 1) * 17 + batch]
             + rw[(4 + tile) * 272 + (row0 + 1) * 17 + batch]
             + rw[(6 + tile) * 272 + (row0 + 1) * 17 + batch];

    float h0 = tanh_(bf2f((u16)(xp2 & 0xffff)) + s0);
    float h1 = tanh_(bf2f((u16)(xp2 >> 16)) + s1);
    float o0 = h0 * bf2f((u16)(zs2 & 0xffff));   // zs already silu'd
    float o1 = h1 * bf2f((u16)(zs2 >> 16));
    u32 opack = (u32)f2bf(o0) | ((u32)f2bf(o1) << 16);
    u32 hpack = (u32)f2bf(h0) | ((u32)f2bf(h1) << 16);

    if (t == T_ - 1) {                           // h_final, dtype-branched
      *(u32*)(sout + pidx) = opack;
      if (fp32o) {
        float* hf32 = (float*)dout + (long)B_ * T_ * D_;
        hf32[batch * D_ + d0]     = h0;
        hf32[batch * D_ + d0 + 1] = h1;
      } else {
        u16* hb = (u16*)dout + (long)B_ * T_ * D_;
        *(u32*)(hb + batch * D_ + d0) = hpack;
      }
      break;                                     // uniform exit
    }

    // --- publish: h store -> wave-local ack drain -> 40-replica flag bump ---
    __hip_atomic_store((u32*)(hn + batch * D_ + d0), hpack,
                       __ATOMIC_RELAXED, __HIP_MEMORY_SCOPE_AGENT);
    asm volatile("s_waitcnt vmcnt(0)" ::: "memory");
    if (lane < 40)
      __hip_atomic_store(fs, (u32)(t + 1),
                         __ATOMIC_RELAXED, __HIP_MEMORY_SCOPE_AGENT);

    // off the critical path: output store + next-step input prefetch
    *(u32*)(sout + pidx) = opack;
    pidx = (long)((t + 1) * B_ + batch) * D_ + d0;
    xp2 = *(const u32*)(xpre + pidx);
    zs2 = *(const u32*)(zs + pidx);
  }
}

// ---------------------------------------------------------------------------
extern "C" void kernel_launch(void* const* d_in, const int* in_sizes, int n_in,
                              void* d_out, int out_size, void* d_ws, size_t ws_size,
                              hipStream_t stream) {
  const void* x     = d_in[0];   // (16,2048,1280)
  const void* W_in  = d_in[1];   // (2560,1280)
  const void* W_out = d_in[2];   // (1280,1280)
  const void* W_x   = d_in[3];   // (1280,1280)
  const void* W_h   = d_in[4];   // (1280,1280)
  const void* bias  = d_in[5];   // (1280,)

  const size_t SZ = (size_t)32768 * D_ * sizeof(u16);  // 83,886,080 B
  char* ws = (char*)d_ws;
  u16* bufA  = (u16*)(ws);                        // x_bf16 -> xpre -> sout (in place)
  u16* bufB  = (u16*)(ws + SZ);                   // x_proj
  u16* wi    = (u16*)(ws + 2 * SZ);               // W_in  bf16 (6,553,600 B)
  u16* wo    = (u16*)(ws + 2 * SZ +  6553600);    // W_out bf16 (3,276,800 B)
  u16* wx    = (u16*)(ws + 2 * SZ +  9830400);    // W_x   bf16
  u16* wh    = (u16*)(ws + 2 * SZ + 13107200);    // W_h   bf16
  u16* bb_   = (u16*)(ws + 2 * SZ + 16384000);    // bias  bf16 (2,560 B)
  u16* hbuf  = (u16*)(ws + 2 * SZ + 16386560);    // 2 x (16 x 1280) bf16 ring (81,920 B)
  u32* flags = (u32*)(ws + 2 * SZ + 16386560 + 81920);   // 40 replicas x 272 u32 (43,520 B)
  int* dflag = (int*)(ws + 2 * SZ + 16386560 + 81920 + 43520);
  u16* zsil  = (u16*)d_out;                       // silu(z) parks in d_out; dead
                                                  // before gemm<2> overwrites it

  hipMemsetAsync(hbuf, 0, 81920 + 43520, stream); // h^0 = 0, all flag replicas = 0

  detect_k<<<1, 256, 0, stream>>>((const u16*)x, dflag);
  cvt_k<<<20480, 256, 0, stream>>>(x,     bufA, 41943040L, dflag);
  cvt_k<<< 1600, 256, 0, stream>>>(W_in,  wi,    3276800L, dflag);
  cvt_k<<<  800, 256, 0, stream>>>(W_out, wo,    1638400L, dflag);
  cvt_k<<<  800, 256, 0, stream>>>(W_x,   wx,    1638400L, dflag);
  cvt_k<<<  800, 256, 0, stream>>>(W_h,   wh,    1638400L, dflag);
  cvt_k<<<    1, 256, 0, stream>>>(bias,  bb_,      1280L, dflag);

  gemm_bt<0><<<dim3(20, 256), 256, 0, stream>>>(bufA, wi, bufB, zsil, nullptr, nullptr, dflag);
  gemm_bt<1><<<dim3(10, 256), 256, 0, stream>>>(bufB, wx, bufA, nullptr, bb_, nullptr, dflag);
  scan_rnn<<<NW, 256, 0, stream>>>(wh, bufA, zsil, bufA, hbuf, flags, d_out, dflag);
  gemm_bt<2><<<dim3(10, 256), 256, 0, stream>>>(bufA, wo, nullptr, nullptr, nullptr, d_out, dflag);
}

// Round 5
// 7694.387 us; speedup vs baseline: 1.2614x; 1.2614x over previous
//
#include <hip/hip_runtime.h>

#define D_  1280
#define T_  2048
#define B_  16

typedef unsigned short u16;
typedef unsigned int   u32;
typedef unsigned long long u64;
typedef __attribute__((ext_vector_type(8))) short bf16x8;   // 8 bf16 = 4 VGPRs
typedef __attribute__((ext_vector_type(4))) float f32x4;
typedef __attribute__((ext_vector_type(4))) int   i32x4;

__device__ __forceinline__ float bf2f(u16 u) {
  union { u32 i; float f; } v; v.i = ((u32)u) << 16; return v.f;
}
__device__ __forceinline__ u16 f2bf(float f) {
  union { float f; u32 i; } v; v.f = f;
  u32 r = v.i + 0x7fffu + ((v.i >> 16) & 1u);   // RNE
  return (u16)(r >> 16);
}
__device__ __forceinline__ float sigm(float x) { return 1.f / (1.f + __expf(-x)); }
__device__ __forceinline__ float tanh_(float x) { return 1.f - 2.f / (__expf(2.f * x) + 1.f); }

// ---------------------------------------------------------------------------
// dtype detection: bf16 halfwords of N(0,1)-scale data have exponent field in
// ~[100,140] nearly always; fp32 low-halfwords are ~random -> count separates.
// ---------------------------------------------------------------------------
__global__ void detect_k(const u16* __restrict__ x, int* __restrict__ dflag) {
  __shared__ int cnt;
  if (threadIdx.x == 0) cnt = 0;
  __syncthreads();
  u16 u = x[threadIdx.x];
  int e = (u >> 7) & 0xFF;
  if (e >= 100 && e <= 140) atomicAdd(&cnt, 1);
  __syncthreads();
  if (threadIdx.x == 0) *dflag = (cnt < 192) ? 1 : 0;   // 1 = fp32 inputs
}

// convert (or copy) n elements to bf16; n arbitrary, 8 elems/thread
__global__ void cvt_k(const void* __restrict__ src, u16* __restrict__ dst,
                      long n, const int* __restrict__ dflag) {
  const int fp32 = *dflag;
  long base = ((long)blockIdx.x * 256 + threadIdx.x) * 8;
  if (base + 8 <= n) {
    if (fp32) {
      const float* s = (const float*)src;
      f32x4 f0 = *(const f32x4*)(s + base);
      f32x4 f1 = *(const f32x4*)(s + base + 4);
      u32 w0 = (u32)f2bf(f0[0]) | ((u32)f2bf(f0[1]) << 16);
      u32 w1 = (u32)f2bf(f0[2]) | ((u32)f2bf(f0[3]) << 16);
      u32 w2 = (u32)f2bf(f1[0]) | ((u32)f2bf(f1[1]) << 16);
      u32 w3 = (u32)f2bf(f1[2]) | ((u32)f2bf(f1[3]) << 16);
      i32x4 o = { (int)w0, (int)w1, (int)w2, (int)w3 };
      *(i32x4*)(dst + base) = o;
    } else {
      *(i32x4*)(dst + base) = *(const i32x4*)((const u16*)src + base);
    }
  } else {
    for (long i = base; i < n; ++i)
      dst[i] = fp32 ? f2bf(((const float*)src)[i]) : ((const u16*)src)[i];
  }
}

// ---------------------------------------------------------------------------
// GEMM: C(M x N) = A(M x K=1280) * B^T, B given as (N x K) row-major bf16.
// 128x128 tile, BK=32, 256 threads = 4 waves in 2x2 grid, 64x64 per wave.
// ---------------------------------------------------------------------------
template<int EPI>
__global__ __launch_bounds__(256, 2) void gemm_bt(
    const u16* __restrict__ A, const u16* __restrict__ B,
    u16* __restrict__ C0, u16* __restrict__ C1,
    const u16* __restrict__ bias,
    void* __restrict__ Cout, const int* __restrict__ dflag)
{
  __shared__ __align__(16) u16 As[128 * 40];
  __shared__ __align__(16) u16 Bs[128 * 40];

  const int fp32o = (EPI == 2) ? *dflag : 0;
  const int tid  = threadIdx.x;
  const int lane = tid & 63;
  const int qq   = lane >> 4, ln = lane & 15;
  const int wave = tid >> 6;
  const int wm   = (wave >> 1) * 64, wn = (wave & 1) * 64;
  const long m0  = (long)blockIdx.y * 128;
  const long n0  = (long)blockIdx.x * 128;

  const int r0 = tid >> 2, c0 = (tid & 3) * 8;
  const int r1 = r0 + 64;

  f32x4 acc[4][4];
  #pragma unroll
  for (int i = 0; i < 4; ++i)
    #pragma unroll
    for (int j = 0; j < 4; ++j) acc[i][j] = (f32x4){0.f, 0.f, 0.f, 0.f};

  for (int kt = 0; kt < D_; kt += 32) {
    i32x4 av0 = *(const i32x4*)(A + (m0 + r0) * D_ + kt + c0);
    i32x4 av1 = *(const i32x4*)(A + (m0 + r1) * D_ + kt + c0);
    i32x4 bv0 = *(const i32x4*)(B + (n0 + r0) * D_ + kt + c0);
    i32x4 bv1 = *(const i32x4*)(B + (n0 + r1) * D_ + kt + c0);
    __syncthreads();                       // previous iter's ds_reads done
    *(i32x4*)(As + r0 * 40 + c0) = av0;
    *(i32x4*)(As + r1 * 40 + c0) = av1;
    *(i32x4*)(Bs + r0 * 40 + c0) = bv0;
    *(i32x4*)(Bs + r1 * 40 + c0) = bv1;
    __syncthreads();

    bf16x8 af[4], bfr[4];
    #pragma unroll
    for (int i = 0; i < 4; ++i)
      af[i] = *(const bf16x8*)(As + (wm + i * 16 + ln) * 40 + qq * 8);
    #pragma unroll
    for (int j = 0; j < 4; ++j)
      bfr[j] = *(const bf16x8*)(Bs + (wn + j * 16 + ln) * 40 + qq * 8);
    #pragma unroll
    for (int i = 0; i < 4; ++i)
      #pragma unroll
      for (int j = 0; j < 4; ++j)
        acc[i][j] = __builtin_amdgcn_mfma_f32_16x16x32_bf16(af[i], bfr[j], acc[i][j], 0, 0, 0);
  }

  #pragma unroll
  for (int i = 0; i < 4; ++i)
    #pragma unroll
    for (int j = 0; j < 4; ++j)
      #pragma unroll
      for (int r = 0; r < 4; ++r) {
        long m = m0 + wm + i * 16 + qq * 4 + r;       // C/D: row = quad*4+reg
        long n = n0 + wn + j * 16 + ln;               //      col = lane&15
        float v = acc[i][j][r];
        if (EPI == 0) {
          float s = v * sigm(v);                      // silu
          long t = m & 2047, bb = m >> 11;
          if (n < D_) C0[m * D_ + n] = f2bf(s);                       // x_proj (b,t,d)
          else        C1[(t * 16 + bb) * D_ + (n - D_)] = f2bf(s);    // silu(z) (t,b,d)
        } else if (EPI == 1) {
          long t = m & 2047, bb = m >> 11;
          C0[(t * 16 + bb) * D_ + n] = f2bf(v + bf2f(bias[n]));       // x_pre (t,b,d)
        } else {
          long bb = m & 15, t = m >> 4;
          long idx = (bb * 2048 + t) * D_ + n;                        // out (b,t,d)
          if (fp32o) ((float*)Cout)[idx] = v;
          else       ((u16*)Cout)[idx]   = f2bf(v);
        }
      }
}

// ---------------------------------------------------------------------------
// Sequential scan, batch-decomposed: the B=16 recurrences are INDEPENDENT, so
// sync domains are per-batch: 16 domains x 16 WGs x 4 waves = 256 WGs (one per
// CU at occupancy 1). Domain b, part p owns output rows [80p,80p+80); wave w
// owns K-slice [320w,320w+320). W_h slice (80x1280) lives in VGPRs (200 regs).
// MFMA B operand = h broadcast into all 16 cols (uniform per-lane address ->
// one LIC line per 16 lanes); all D cols equal, col 0 used.
// Cross-WG h (2.5KB/domain/step) moves via relaxed agent-scope u32 atomics;
// publish = h stores -> wave vmcnt drain -> monotone wave-flag. Poll set =
// 16 producer wave-flags (WGs [4w,4w+4)) + OWN WG's 4 sibling flags: the
// sibling gate closes the barrier-lap race (a wave cannot enter step t until
// every sibling finished step t-1 => s_barrier arrivals stay iteration-
// aligned), and the union of sibling poll sets = all 16 domain WGs, which
// keeps the depth-2 h ring safe (h^{t+2} store implies every domain wave
// finished reading h^t).
// Liveness: domains share NOTHING (disjoint flag lines, disjoint h rings), so
// even partial residency self-resolves (resident domains finish and free CUs).
// Belt-and-braces: a global spin budget (~350ms) converts any residual sync
// pathology into a terminating wrong-answer run (diagnosable) instead of a
// container-killing hang.
// ---------------------------------------------------------------------------
__global__ __launch_bounds__(256, 1) void scan_rnn(
    const u16* __restrict__ Wh, const u16* __restrict__ xpre,
    const u16* __restrict__ zs, u16* __restrict__ sout,
    u16* __restrict__ hbuf, u32* __restrict__ flags,
    void* __restrict__ dout, const int* __restrict__ dflag)
{
  const int fp32o = *dflag;
  const int g    = blockIdx.x;
  const int xcd  = g & 7;                  // likely XCD under round-robin
  const int slot = g >> 3;                 // 0..31
  const int b    = (slot >> 4) * 8 + xcd;  // domain (batch) 0..15, XCD-clustered
  const int p    = slot & 15;              // part: rows [80p, 80p+80)
  const int tid  = threadIdx.x;
  const int lane = tid & 63;
  const int w    = tid >> 6;               // wave: K-slice [320w, 320w+320)
  const int qq   = lane >> 4, ln = lane & 15;

  // persistent W_h fragments: 5 m-tiles x 10 k-chunks, A[m=ln][k=qq*8+j]
  bf16x8 wfrag[5][10];
  #pragma unroll
  for (int i = 0; i < 5; ++i) {
    const u16* wrow = Wh + (long)(p * 80 + i * 16 + ln) * D_ + w * 320;
    #pragma unroll
    for (int c = 0; c < 10; ++c)
      wfrag[i][c] = *(const bf16x8*)(wrow + c * 32 + qq * 8);
  }

  __shared__ float red[2][320];            // [ring][wave*80 + row]

  // poll set: lanes 0-15 -> producers (WG 4w+(l>>2), wave l&3);
  //           lanes 16-19 -> own WG sibling flags; rest duplicate a producer.
  int pl;
  if      (lane < 16) pl = (4 * w + (lane >> 2)) * 4 + (lane & 3);
  else if (lane < 20) pl = p * 4 + (lane - 16);
  else                pl = (4 * w) * 4;
  const u32* fl = flags + b * 256 + pl;
  u32*       fs = flags + b * 256 + p * 4 + w;

  // epilogue: lane l<20 owns row erow = 20w+l, global d = 80p+erow
  const int erow = 20 * w + lane;
  const int ed   = 80 * p + erow;
  const int ep   = (lane < 20);

  u16* hb0 = hbuf + b * 2560;              // per-domain depth-2 ring (2x1280)

  long pidx = (long)(0 * B_ + b) * D_ + ed;
  u16 xp = 0, zv = 0;
  if (ep) { xp = xpre[pidx]; zv = zs[pidx]; }

  int budget = 1 << 21;                    // global spin budget (anti-hang)

  for (int t = 0; t < T_; ++t) {
    const u16* hc = hb0 + (t & 1) * D_;
    u16*       hn = hb0 + ((t + 1) & 1) * D_;

    // --- poll producers + siblings (all flags monotone, LIC-hot) ---
    {
      const u32 tgt = (u32)t;
      for (;;) {
        u32 v = __hip_atomic_load(fl, __ATOMIC_RELAXED, __HIP_MEMORY_SCOPE_AGENT);
        if (__all(v >= tgt) || --budget < 0) break;
      }
    }

    // --- load my 640B h^t slice (uniform across ln -> broadcast lines) ---
    u64 hq[20];
    #pragma unroll
    for (int c = 0; c < 10; ++c) {
      const u64* hr = (const u64*)(hc + w * 320 + c * 32 + qq * 8);
      hq[c * 2 + 0] = __hip_atomic_load(hr + 0,
                          __ATOMIC_RELAXED, __HIP_MEMORY_SCOPE_AGENT);
      hq[c * 2 + 1] = __hip_atomic_load(hr + 1,
                          __ATOMIC_RELAXED, __HIP_MEMORY_SCOPE_AGENT);
    }

    // --- MFMA: 5 independent chains of 10 (B cols all = h) ---
    f32x4 acc[5];
    #pragma unroll
    for (int i = 0; i < 5; ++i) acc[i] = (f32x4){0.f, 0.f, 0.f, 0.f};
    #pragma unroll
    for (int c = 0; c < 10; ++c) {
      union { u64 q[2]; bf16x8 v; } hu;
      hu.q[0] = hq[c * 2 + 0];
      hu.q[1] = hq[c * 2 + 1];
      #pragma unroll
      for (int i = 0; i < 5; ++i)
        acc[i] = __builtin_amdgcn_mfma_f32_16x16x32_bf16(wfrag[i][c], hu.v, acc[i], 0, 0, 0);
    }

    // --- cross-wave reduce (double-buffered, one barrier per step) ---
    float* rw = red[t & 1];
    if (ln == 0) {
      #pragma unroll
      for (int i = 0; i < 5; ++i)
        #pragma unroll
        for (int r = 0; r < 4; ++r)
          rw[w * 80 + i * 16 + qq * 4 + r] = acc[i][r];
    }
    __syncthreads();

    float h = 0.f, o = 0.f;
    u16 hbf = 0;
    if (ep) {
      float s = rw[0 * 80 + erow] + rw[1 * 80 + erow]
              + rw[2 * 80 + erow] + rw[3 * 80 + erow];
      h = tanh_(bf2f(xp) + s);
      o = h * bf2f(zv);                    // zs already silu'd
      hbf = f2bf(h);
    }

    // pack h pairs for u32 atomic stores (even lanes get partner's high half)
    u32 hx  = (u32)hbf;
    u32 px  = (u32)__shfl_xor((int)hx, 1);
    u32 hpk = hx | (px << 16);

    if (t == T_ - 1) {                     // final step: outputs, no publish
      if (ep) {
        sout[pidx] = f2bf(o);
        if (fp32o) {
          float* hf = (float*)dout + (long)B_ * T_ * D_;
          hf[b * D_ + ed] = h;
        } else {
          u16* hb = (u16*)dout + (long)B_ * T_ * D_;
          hb[b * D_ + ed] = hbf;
        }
      }
      break;                               // uniform exit
    }

    // --- publish: h stores -> wave-local ack drain -> monotone wave-flag ---
    if (ep && !(lane & 1))
      __hip_atomic_store((u32*)(hn + ed), hpk,
                         __ATOMIC_RELAXED, __HIP_MEMORY_SCOPE_AGENT);
    asm volatile("s_waitcnt vmcnt(0)" ::: "memory");
    if (lane == 0)
      __hip_atomic_store(fs, (u32)(t + 1),
                         __ATOMIC_RELAXED, __HIP_MEMORY_SCOPE_AGENT);

    // off the critical path: output store + next-step input prefetch
    if (ep) sout[pidx] = f2bf(o);
    pidx = (long)((t + 1) * B_ + b) * D_ + ed;
    if (ep) { xp = xpre[pidx]; zv = zs[pidx]; }
  }
}

// ---------------------------------------------------------------------------
extern "C" void kernel_launch(void* const* d_in, const int* in_sizes, int n_in,
                              void* d_out, int out_size, void* d_ws, size_t ws_size,
                              hipStream_t stream) {
  const void* x     = d_in[0];   // (16,2048,1280)
  const void* W_in  = d_in[1];   // (2560,1280)
  const void* W_out = d_in[2];   // (1280,1280)
  const void* W_x   = d_in[3];   // (1280,1280)
  const void* W_h   = d_in[4];   // (1280,1280)
  const void* bias  = d_in[5];   // (1280,)

  const size_t SZ = (size_t)32768 * D_ * sizeof(u16);  // 83,886,080 B
  char* ws = (char*)d_ws;
  u16* bufA  = (u16*)(ws);                        // x_bf16 -> xpre -> sout (in place)
  u16* bufB  = (u16*)(ws + SZ);                   // x_proj
  u16* wi    = (u16*)(ws + 2 * SZ);               // W_in  bf16 (6,553,600 B)
  u16* wo    = (u16*)(ws + 2 * SZ +  6553600);    // W_out bf16 (3,276,800 B)
  u16* wx    = (u16*)(ws + 2 * SZ +  9830400);    // W_x   bf16
  u16* wh    = (u16*)(ws + 2 * SZ + 13107200);    // W_h   bf16
  u16* bb_   = (u16*)(ws + 2 * SZ + 16384000);    // bias  bf16 (2,560 B)
  u16* hbuf  = (u16*)(ws + 2 * SZ + 16386560);    // 16 domains x 2 x 1280 bf16 (81,920 B)
  u32* flags = (u32*)(ws + 2 * SZ + 16386560 + 81920);   // 16 x 256 u32 (16,384 B)
  int* dflag = (int*)(ws + 2 * SZ + 16386560 + 81920 + 16384);
  u16* zsil  = (u16*)d_out;                       // silu(z) parks in d_out; dead
                                                  // before gemm<2> overwrites it

  hipMemsetAsync(hbuf, 0, 81920 + 16384, stream); // h^0 = 0, all flags = 0

  detect_k<<<1, 256, 0, stream>>>((const u16*)x, dflag);
  cvt_k<<<20480, 256, 0, stream>>>(x,     bufA, 41943040L, dflag);
  cvt_k<<< 1600, 256, 0, stream>>>(W_in,  wi,    3276800L, dflag);
  cvt_k<<<  800, 256, 0, stream>>>(W_out, wo,    1638400L, dflag);
  cvt_k<<<  800, 256, 0, stream>>>(W_x,   wx,    1638400L, dflag);
  cvt_k<<<  800, 256, 0, stream>>>(W_h,   wh,    1638400L, dflag);
  cvt_k<<<    1, 256, 0, stream>>>(bias,  bb_,      1280L, dflag);

  gemm_bt<0><<<dim3(20, 256), 256, 0, stream>>>(bufA, wi, bufB, zsil, nullptr, nullptr, dflag);
  gemm_bt<1><<<dim3(10, 256), 256, 0, stream>>>(bufB, wx, bufA, nullptr, bb_, nullptr, dflag);
  scan_rnn<<<256, 256, 0, stream>>>(wh, bufA, zsil, bufA, hbuf, flags, d_out, dflag);
  gemm_bt<2><<<dim3(10, 256), 256, 0, stream>>>(bufA, wo, nullptr, nullptr, nullptr, d_out, dflag);
}